// Round 3
// baseline (899.458 us; speedup 1.0000x reference)
//
#include <hip/hip_runtime.h>
#include <hip/hip_bf16.h>
#include <math.h>

#define NUMC 10000
#define DIMS 128
#define SZM  50
#define FD   512
#define NB   64
#define NL   200
#define NTOK (NB*NL)
#define TPB  16     // tokens per block (prep / fp kernels)
#define KC   64     // K-chunk staged in LDS (prep)
#define NG   2      // m-groups in scan
#define MG   25     // m's per group

// ws layout (float offsets)
#define OFF_K  ((size_t)0)
#define OFF_W  (OFF_K + (size_t)NTOK*DIMS)          // [NTOK][64], plain m-major (0..49), padded to 64
#define OFF_E  (OFF_W + (size_t)NTOK*64)
#define OFF_A  (OFF_E + (size_t)NTOK*DIMS)
#define OFF_PR (OFF_A + (size_t)NTOK*DIMS)          // [NG][NTOK][DIMS]

__device__ __forceinline__ float sigmoidf_(float x){ return 1.0f/(1.0f+expf(-x)); }

__global__ __launch_bounds__(256,6) void prep_kernel(
    const int* __restrict__ q, const int* __restrict__ r,
    const float* __restrict__ k_emb, const float* __restrict__ v_emb,
    const float* __restrict__ W1, const float* __restrict__ b1,
    const float* __restrict__ W2, const float* __restrict__ b2,
    const float* __restrict__ Mk,
    const float* __restrict__ We, const float* __restrict__ be,
    const float* __restrict__ Wa, const float* __restrict__ ba,
    float* __restrict__ ws)
{
    __shared__ float ek[TPB][KC+4];
    __shared__ float ev[TPB][KC+4];
    __shared__ float sk[TPB][DIMS+4];
    __shared__ float sv[TPB][DIMS+4];

    const int tid  = threadIdx.x;
    const int base = blockIdx.x * TPB;

    // staging role: thread loads one float4 of one token row per chunk
    const int tr = tid >> 4;          // token 0..15
    const int c4 = (tid & 15) * 4;    // float offset in chunk
    const float* krow = k_emb + (size_t)q[base+tr]*FD + c4;
    const float* vrow = v_emb + ((size_t)q[base+tr] + (size_t)NUMC*(size_t)r[base+tr])*FD + c4;

    // compute role: d-column, 8 tokens per thread
    const int d    = tid & 127;
    const int half = tid >> 7;
    const int t0   = half * 8;

    float kacc[8], vacc[8];
    {
        float bb1=b1[d], bb2=b2[d];
        #pragma unroll
        for (int t=0;t<8;t++){ kacc[t]=bb1; vacc[t]=bb2; }
    }

    for (int i0=0; i0<FD; i0+=KC){
        __syncthreads();
        *(float4*)&ek[tr][c4] = *(const float4*)(krow + i0);
        *(float4*)&ev[tr][c4] = *(const float4*)(vrow + i0);
        __syncthreads();

        #pragma unroll
        for (int i=0;i<KC;i+=4){
            float w10=W1[(i0+i+0)*DIMS+d], w11=W1[(i0+i+1)*DIMS+d],
                  w12=W1[(i0+i+2)*DIMS+d], w13=W1[(i0+i+3)*DIMS+d];
            float w20=W2[(i0+i+0)*DIMS+d], w21=W2[(i0+i+1)*DIMS+d],
                  w22=W2[(i0+i+2)*DIMS+d], w23=W2[(i0+i+3)*DIMS+d];
            #pragma unroll
            for (int t=0;t<8;t++){
                float4 a4 = *(const float4*)&ek[t0+t][i];
                float4 b4 = *(const float4*)&ev[t0+t][i];
                kacc[t]=fmaf(a4.x,w10,fmaf(a4.y,w11,fmaf(a4.z,w12,fmaf(a4.w,w13,kacc[t]))));
                vacc[t]=fmaf(b4.x,w20,fmaf(b4.y,w21,fmaf(b4.z,w22,fmaf(b4.w,w23,vacc[t]))));
            }
        }
    }
    #pragma unroll
    for (int t=0;t<8;t++){
        sk[t0+t][d]=kacc[t];
        sv[t0+t][d]=vacc[t];
        ws[OFF_K + (size_t)(base+t0+t)*DIMS + d] = kacc[t];
    }
    __syncthreads();

    // softmax(k @ Mk^T): 16 lanes per token, 4 m's per lane
    {
        const int t  = tid >> 4;
        const int ml = tid & 15;
        float lg[4];
        #pragma unroll
        for (int j=0;j<4;j++){
            int m = ml + j*16;
            float s = -1e30f;
            if (m < SZM){
                s = 0.f;
                const float* mk = Mk + (size_t)m*DIMS;
                #pragma unroll
                for (int i=0;i<DIMS;i+=4){
                    float4 kk = *(const float4*)&sk[t][i];
                    float4 m4 = *(const float4*)(mk+i);
                    s += kk.x*m4.x + kk.y*m4.y + kk.z*m4.z + kk.w*m4.w;
                }
            }
            lg[j]=s;
        }
        float mx = fmaxf(fmaxf(lg[0],lg[1]),fmaxf(lg[2],lg[3]));
        #pragma unroll
        for (int o=1;o<16;o<<=1) mx = fmaxf(mx, __shfl_xor(mx,o));
        float ex[4]; float sm=0.f;
        #pragma unroll
        for (int j=0;j<4;j++){
            int m = ml + j*16;
            ex[j] = (m<SZM) ? expf(lg[j]-mx) : 0.f;
            sm += ex[j];
        }
        #pragma unroll
        for (int o=1;o<16;o<<=1) sm += __shfl_xor(sm,o);
        float inv = 1.f/sm;
        #pragma unroll
        for (int j=0;j<4;j++){
            int m = ml + j*16;
            if (m<SZM) ws[OFF_W + (size_t)(base+t)*64 + m] = ex[j]*inv;
        }
    }

    // e = sigmoid(v@We+be), a = tanh(v@Wa+ba)   (K=128)
    float eacc[8], aacc[8];
    {
        float bbe=be[d], bba=ba[d];
        #pragma unroll
        for (int t=0;t<8;t++){ eacc[t]=bbe; aacc[t]=bba; }
    }
    for (int i=0;i<DIMS;i+=4){
        float e0=We[(i+0)*DIMS+d], e1=We[(i+1)*DIMS+d], e2=We[(i+2)*DIMS+d], e3=We[(i+3)*DIMS+d];
        float a0=Wa[(i+0)*DIMS+d], a1=Wa[(i+1)*DIMS+d], a2=Wa[(i+2)*DIMS+d], a3=Wa[(i+3)*DIMS+d];
        #pragma unroll
        for (int t=0;t<8;t++){
            float4 v4 = *(const float4*)&sv[t0+t][i];
            eacc[t]=fmaf(v4.x,e0,fmaf(v4.y,e1,fmaf(v4.z,e2,fmaf(v4.w,e3,eacc[t]))));
            aacc[t]=fmaf(v4.x,a0,fmaf(v4.y,a1,fmaf(v4.z,a2,fmaf(v4.w,a3,aacc[t]))));
        }
    }
    #pragma unroll
    for (int t=0;t<8;t++){
        size_t o=(size_t)(base+t0+t)*DIMS+d;
        ws[OFF_E+o]=sigmoidf_(eacc[t]);
        ws[OFF_A+o]=tanhf(aacc[t]);
    }
}

__global__ __launch_bounds__(128) void scan_kernel(const float* __restrict__ Mv0, float* __restrict__ ws)
{
    const int b = blockIdx.x;
    const int g = blockIdx.y;
    const int d = threadIdx.x;

    const float* wb = ws + OFF_W + (size_t)b*NL*64 + g*MG;
    const float* eb = ws + OFF_E + (size_t)b*NL*DIMS + d;
    const float* ab = ws + OFF_A + (size_t)b*NL*DIMS + d;
    float* pr = ws + OFF_PR + ((size_t)g*NTOK + (size_t)b*NL)*DIMS + d;

    float Mv[MG];
    #pragma unroll
    for (int m=0;m<MG;m++) Mv[m] = Mv0[(g*MG+m)*DIMS + d];

    float wA[MG], wB[MG];
    float eA,aA,eB,aB;
    #pragma unroll
    for (int m=0;m<MG;m++) wA[m]=wb[m];
    eA=eb[0]; aA=ab[0];

    for (int t=0;t<NL;t+=2){
        #pragma unroll
        for (int m=0;m<MG;m++) wB[m]=wb[(size_t)(t+1)*64+m];
        eB=eb[(size_t)(t+1)*DIMS]; aB=ab[(size_t)(t+1)*DIMS];

        float rt=0.f;
        #pragma unroll
        for (int m=0;m<MG;m++){
            float c=wA[m];
            rt=fmaf(c,Mv[m],rt);
            float t1=c*eA, t2=c*aA;
            Mv[m]=Mv[m]+fmaf(-t1,Mv[m],t2);
        }
        pr[(size_t)t*DIMS]=rt;

        if (t+2<NL){
            #pragma unroll
            for (int m=0;m<MG;m++) wA[m]=wb[(size_t)(t+2)*64+m];
            eA=eb[(size_t)(t+2)*DIMS]; aA=ab[(size_t)(t+2)*DIMS];
        }

        rt=0.f;
        #pragma unroll
        for (int m=0;m<MG;m++){
            float c=wB[m];
            rt=fmaf(c,Mv[m],rt);
            float t1=c*eB, t2=c*aB;
            Mv[m]=Mv[m]+fmaf(-t1,Mv[m],t2);
        }
        pr[(size_t)(t+1)*DIMS]=rt;
    }
}

__global__ __launch_bounds__(256) void fp_kernel(
    const float* __restrict__ ws,
    const float* __restrict__ Wf, const float* __restrict__ bf,
    const float* __restrict__ Wp, const float* __restrict__ bp,
    float* __restrict__ out)
{
    __shared__ float sr [TPB][DIMS+4];
    __shared__ float skk[TPB][DIMS+4];
    __shared__ float pf [TPB][DIMS+4];
    const int tid  = threadIdx.x;
    const int d    = tid & 127;
    const int half = tid >> 7;
    const int base = blockIdx.x*TPB;
    const int t0   = half*8;

    #pragma unroll
    for (int t=0;t<8;t++){
        size_t tok=(size_t)base+t0+t;
        sr [t0+t][d]= ws[OFF_PR + tok*DIMS + d] + ws[OFF_PR + ((size_t)NTOK+tok)*DIMS + d];
        skk[t0+t][d]= ws[OFF_K + tok*DIMS + d];
    }
    __syncthreads();

    float facc[8];
    {
        float bfj=bf[d];
        #pragma unroll
        for (int t=0;t<8;t++) facc[t]=bfj;
    }
    for (int i=0;i<DIMS;i+=4){
        float wt0=Wf[(i+0)*DIMS+d],wt1=Wf[(i+1)*DIMS+d],wt2=Wf[(i+2)*DIMS+d],wt3=Wf[(i+3)*DIMS+d];
        float wb0=Wf[(DIMS+i+0)*DIMS+d],wb1=Wf[(DIMS+i+1)*DIMS+d],wb2=Wf[(DIMS+i+2)*DIMS+d],wb3=Wf[(DIMS+i+3)*DIMS+d];
        #pragma unroll
        for (int t=0;t<8;t++){
            float4 r4=*(const float4*)&sr [t0+t][i];
            float4 k4=*(const float4*)&skk[t0+t][i];
            facc[t]=fmaf(r4.x,wt0,fmaf(r4.y,wt1,fmaf(r4.z,wt2,fmaf(r4.w,wt3,facc[t]))));
            facc[t]=fmaf(k4.x,wb0,fmaf(k4.y,wb1,fmaf(k4.z,wb2,fmaf(k4.w,wb3,facc[t]))));
        }
    }
    {
        float wpj=Wp[d];
        #pragma unroll
        for (int t=0;t<8;t++) pf[t0+t][d]=tanhf(facc[t])*wpj;
    }
    __syncthreads();
    if (tid<TPB){
        float s=bp[0];
        for (int jj=0;jj<DIMS;jj++) s+=pf[tid][jj];
        out[base+tid]=sigmoidf_(s);
    }
}

extern "C" void kernel_launch(void* const* d_in, const int* in_sizes, int n_in,
                              void* d_out, int out_size, void* d_ws, size_t ws_size,
                              hipStream_t stream)
{
    const int*   q     = (const int*)  d_in[0];
    const int*   r     = (const int*)  d_in[1];
    /* d_in[2] = diff (unused) */
    const float* k_emb = (const float*)d_in[3];
    const float* v_emb = (const float*)d_in[4];
    const float* W1    = (const float*)d_in[5];
    const float* b1    = (const float*)d_in[6];
    const float* W2    = (const float*)d_in[7];
    const float* b2    = (const float*)d_in[8];
    const float* Mk    = (const float*)d_in[9];
    const float* Mv0   = (const float*)d_in[10];
    const float* We    = (const float*)d_in[11];
    const float* be    = (const float*)d_in[12];
    const float* Wa    = (const float*)d_in[13];
    const float* ba    = (const float*)d_in[14];
    const float* Wf    = (const float*)d_in[15];
    const float* bf    = (const float*)d_in[16];
    const float* Wp    = (const float*)d_in[17];
    const float* bp    = (const float*)d_in[18];

    float* ws  = (float*)d_ws;
    float* out = (float*)d_out;

    prep_kernel<<<NTOK/TPB, 256, 0, stream>>>(q,r,k_emb,v_emb,W1,b1,W2,b2,Mk,We,be,Wa,ba,ws);
    scan_kernel<<<dim3(NB,NG), 128, 0, stream>>>(Mv0, ws);
    fp_kernel<<<NTOK/TPB, 256, 0, stream>>>(ws, Wf, bf, Wp, bp, out);
}

// Round 4
// 382.493 us; speedup vs baseline: 2.3516x; 2.3516x over previous
//
#include <hip/hip_runtime.h>
#include <hip/hip_bf16.h>
#include <math.h>

#define NUMC 10000
#define DIMS 128
#define SZM  50
#define FD   512
#define NB   64
#define NL   200
#define NTOK (NB*NL)
#define TPB  16     // tokens per block (prep / fp kernels)
#define KC   64     // K-chunk staged in LDS (prep)
#define NG   2      // m-groups in scan
#define MG   25     // m's per group

// ws layout (float offsets)
#define OFF_K  ((size_t)0)
#define OFF_W  (OFF_K + (size_t)NTOK*DIMS)          // [NTOK][64], plain m-major (0..49), padded to 64
#define OFF_E  (OFF_W + (size_t)NTOK*64)
#define OFF_A  (OFF_E + (size_t)NTOK*DIMS)
#define OFF_PR (OFF_A + (size_t)NTOK*DIMS)          // [NG][NTOK][DIMS]

__device__ __forceinline__ float sigmoidf_(float x){ return 1.0f/(1.0f+expf(-x)); }

// NOTE: plain __launch_bounds__(256) — min-wave hints (256,4)/(256,6) forced
// VGPR caps of 64/40 and produced 0.4–1.1 GB of scratch spill traffic
// (rounds 2–3). Spills cost far more than occupancy buys here.
__global__ __launch_bounds__(256) void prep_kernel(
    const int* __restrict__ q, const int* __restrict__ r,
    const float* __restrict__ k_emb, const float* __restrict__ v_emb,
    const float* __restrict__ W1, const float* __restrict__ b1,
    const float* __restrict__ W2, const float* __restrict__ b2,
    const float* __restrict__ Mk,
    const float* __restrict__ We, const float* __restrict__ be,
    const float* __restrict__ Wa, const float* __restrict__ ba,
    float* __restrict__ ws)
{
    __shared__ float ek[TPB][KC+4];
    __shared__ float ev[TPB][KC+4];
    __shared__ float sk[TPB][DIMS+4];
    __shared__ float sv[TPB][DIMS+4];

    const int tid  = threadIdx.x;
    const int base = blockIdx.x * TPB;

    // staging role: thread loads one float4 of one token row per chunk
    const int tr = tid >> 4;          // token 0..15
    const int c4 = (tid & 15) * 4;    // float offset in chunk
    const float* krow = k_emb + (size_t)q[base+tr]*FD + c4;
    const float* vrow = v_emb + ((size_t)q[base+tr] + (size_t)NUMC*(size_t)r[base+tr])*FD + c4;

    // compute role: d-column, 8 tokens per thread
    const int d    = tid & 127;
    const int half = tid >> 7;
    const int t0   = half * 8;

    float kacc[8], vacc[8];
    {
        float bb1=b1[d], bb2=b2[d];
        #pragma unroll
        for (int t=0;t<8;t++){ kacc[t]=bb1; vacc[t]=bb2; }
    }

    // prefetch chunk 0 into registers
    float4 nk = *(const float4*)(krow);
    float4 nv = *(const float4*)(vrow);

    for (int i0=0; i0<FD; i0+=KC){
        __syncthreads();                       // prior compute done reading LDS
        *(float4*)&ek[tr][c4] = nk;
        *(float4*)&ev[tr][c4] = nv;
        __syncthreads();
        if (i0+KC < FD){                       // issue next chunk's loads early;
            nk = *(const float4*)(krow + i0 + KC);   // latency hides under compute
            nv = *(const float4*)(vrow + i0 + KC);
        }

        #pragma unroll
        for (int i=0;i<KC;i+=4){
            float w10=W1[(i0+i+0)*DIMS+d], w11=W1[(i0+i+1)*DIMS+d],
                  w12=W1[(i0+i+2)*DIMS+d], w13=W1[(i0+i+3)*DIMS+d];
            float w20=W2[(i0+i+0)*DIMS+d], w21=W2[(i0+i+1)*DIMS+d],
                  w22=W2[(i0+i+2)*DIMS+d], w23=W2[(i0+i+3)*DIMS+d];
            #pragma unroll
            for (int t=0;t<8;t++){
                float4 a4 = *(const float4*)&ek[t0+t][i];
                float4 b4 = *(const float4*)&ev[t0+t][i];
                kacc[t]=fmaf(a4.x,w10,fmaf(a4.y,w11,fmaf(a4.z,w12,fmaf(a4.w,w13,kacc[t]))));
                vacc[t]=fmaf(b4.x,w20,fmaf(b4.y,w21,fmaf(b4.z,w22,fmaf(b4.w,w23,vacc[t]))));
            }
        }
    }
    #pragma unroll
    for (int t=0;t<8;t++){
        sk[t0+t][d]=kacc[t];
        sv[t0+t][d]=vacc[t];
        ws[OFF_K + (size_t)(base+t0+t)*DIMS + d] = kacc[t];
    }
    __syncthreads();

    // softmax(k @ Mk^T): 16 lanes per token, 4 m's per lane
    {
        const int t  = tid >> 4;
        const int ml = tid & 15;
        float lg[4];
        #pragma unroll
        for (int j=0;j<4;j++){
            int m = ml + j*16;
            float s = -1e30f;
            if (m < SZM){
                s = 0.f;
                const float* mk = Mk + (size_t)m*DIMS;
                #pragma unroll
                for (int i=0;i<DIMS;i+=4){
                    float4 kk = *(const float4*)&sk[t][i];
                    float4 m4 = *(const float4*)(mk+i);
                    s += kk.x*m4.x + kk.y*m4.y + kk.z*m4.z + kk.w*m4.w;
                }
            }
            lg[j]=s;
        }
        float mx = fmaxf(fmaxf(lg[0],lg[1]),fmaxf(lg[2],lg[3]));
        #pragma unroll
        for (int o=1;o<16;o<<=1) mx = fmaxf(mx, __shfl_xor(mx,o));
        float ex[4]; float sm=0.f;
        #pragma unroll
        for (int j=0;j<4;j++){
            int m = ml + j*16;
            ex[j] = (m<SZM) ? expf(lg[j]-mx) : 0.f;
            sm += ex[j];
        }
        #pragma unroll
        for (int o=1;o<16;o<<=1) sm += __shfl_xor(sm,o);
        float inv = 1.f/sm;
        #pragma unroll
        for (int j=0;j<4;j++){
            int m = ml + j*16;
            if (m<SZM) ws[OFF_W + (size_t)(base+t)*64 + m] = ex[j]*inv;
        }
    }

    // e = sigmoid(v@We+be), a = tanh(v@Wa+ba)   (K=128)
    float eacc[8], aacc[8];
    {
        float bbe=be[d], bba=ba[d];
        #pragma unroll
        for (int t=0;t<8;t++){ eacc[t]=bbe; aacc[t]=bba; }
    }
    for (int i=0;i<DIMS;i+=4){
        float e0=We[(i+0)*DIMS+d], e1=We[(i+1)*DIMS+d], e2=We[(i+2)*DIMS+d], e3=We[(i+3)*DIMS+d];
        float a0=Wa[(i+0)*DIMS+d], a1=Wa[(i+1)*DIMS+d], a2=Wa[(i+2)*DIMS+d], a3=Wa[(i+3)*DIMS+d];
        #pragma unroll
        for (int t=0;t<8;t++){
            float4 v4 = *(const float4*)&sv[t0+t][i];
            eacc[t]=fmaf(v4.x,e0,fmaf(v4.y,e1,fmaf(v4.z,e2,fmaf(v4.w,e3,eacc[t]))));
            aacc[t]=fmaf(v4.x,a0,fmaf(v4.y,a1,fmaf(v4.z,a2,fmaf(v4.w,a3,aacc[t]))));
        }
    }
    #pragma unroll
    for (int t=0;t<8;t++){
        size_t o=(size_t)(base+t0+t)*DIMS+d;
        ws[OFF_E+o]=sigmoidf_(eacc[t]);
        ws[OFF_A+o]=tanhf(aacc[t]);
    }
}

__global__ __launch_bounds__(128) void scan_kernel(const float* __restrict__ Mv0, float* __restrict__ ws)
{
    const int b = blockIdx.x;
    const int g = blockIdx.y;
    const int d = threadIdx.x;

    const float* wb = ws + OFF_W + (size_t)b*NL*64 + g*MG;
    const float* eb = ws + OFF_E + (size_t)b*NL*DIMS + d;
    const float* ab = ws + OFF_A + (size_t)b*NL*DIMS + d;
    float* pr = ws + OFF_PR + ((size_t)g*NTOK + (size_t)b*NL)*DIMS + d;

    float Mv[MG];
    #pragma unroll
    for (int m=0;m<MG;m++) Mv[m] = Mv0[(g*MG+m)*DIMS + d];

    float wA[MG], wB[MG];
    float eA,aA,eB,aB;
    #pragma unroll
    for (int m=0;m<MG;m++) wA[m]=wb[m];
    eA=eb[0]; aA=ab[0];

    for (int t=0;t<NL;t+=2){
        #pragma unroll
        for (int m=0;m<MG;m++) wB[m]=wb[(size_t)(t+1)*64+m];
        eB=eb[(size_t)(t+1)*DIMS]; aB=ab[(size_t)(t+1)*DIMS];

        float rt=0.f;
        #pragma unroll
        for (int m=0;m<MG;m++){
            float c=wA[m];
            rt=fmaf(c,Mv[m],rt);
            float t1=c*eA, t2=c*aA;
            Mv[m]=Mv[m]+fmaf(-t1,Mv[m],t2);
        }
        pr[(size_t)t*DIMS]=rt;

        if (t+2<NL){
            #pragma unroll
            for (int m=0;m<MG;m++) wA[m]=wb[(size_t)(t+2)*64+m];
            eA=eb[(size_t)(t+2)*DIMS]; aA=ab[(size_t)(t+2)*DIMS];
        }

        rt=0.f;
        #pragma unroll
        for (int m=0;m<MG;m++){
            float c=wB[m];
            rt=fmaf(c,Mv[m],rt);
            float t1=c*eB, t2=c*aB;
            Mv[m]=Mv[m]+fmaf(-t1,Mv[m],t2);
        }
        pr[(size_t)(t+1)*DIMS]=rt;
    }
}

__global__ __launch_bounds__(256) void fp_kernel(
    const float* __restrict__ ws,
    const float* __restrict__ Wf, const float* __restrict__ bf,
    const float* __restrict__ Wp, const float* __restrict__ bp,
    float* __restrict__ out)
{
    __shared__ float sr [TPB][DIMS+4];
    __shared__ float skk[TPB][DIMS+4];
    __shared__ float pf [TPB][DIMS+4];
    const int tid  = threadIdx.x;
    const int d    = tid & 127;
    const int half = tid >> 7;
    const int base = blockIdx.x*TPB;
    const int t0   = half*8;

    #pragma unroll
    for (int t=0;t<8;t++){
        size_t tok=(size_t)base+t0+t;
        sr [t0+t][d]= ws[OFF_PR + tok*DIMS + d] + ws[OFF_PR + ((size_t)NTOK+tok)*DIMS + d];
        skk[t0+t][d]= ws[OFF_K + tok*DIMS + d];
    }
    __syncthreads();

    float facc[8];
    {
        float bfj=bf[d];
        #pragma unroll
        for (int t=0;t<8;t++) facc[t]=bfj;
    }
    for (int i=0;i<DIMS;i+=4){
        float wt0=Wf[(i+0)*DIMS+d],wt1=Wf[(i+1)*DIMS+d],wt2=Wf[(i+2)*DIMS+d],wt3=Wf[(i+3)*DIMS+d];
        float wb0=Wf[(DIMS+i+0)*DIMS+d],wb1=Wf[(DIMS+i+1)*DIMS+d],wb2=Wf[(DIMS+i+2)*DIMS+d],wb3=Wf[(DIMS+i+3)*DIMS+d];
        #pragma unroll
        for (int t=0;t<8;t++){
            float4 r4=*(const float4*)&sr [t0+t][i];
            float4 k4=*(const float4*)&skk[t0+t][i];
            facc[t]=fmaf(r4.x,wt0,fmaf(r4.y,wt1,fmaf(r4.z,wt2,fmaf(r4.w,wt3,facc[t]))));
            facc[t]=fmaf(k4.x,wb0,fmaf(k4.y,wb1,fmaf(k4.z,wb2,fmaf(k4.w,wb3,facc[t]))));
        }
    }
    {
        float wpj=Wp[d];
        #pragma unroll
        for (int t=0;t<8;t++) pf[t0+t][d]=tanhf(facc[t])*wpj;
    }
    __syncthreads();
    if (tid<TPB){
        float s=bp[0];
        for (int jj=0;jj<DIMS;jj++) s+=pf[tid][jj];
        out[base+tid]=sigmoidf_(s);
    }
}

extern "C" void kernel_launch(void* const* d_in, const int* in_sizes, int n_in,
                              void* d_out, int out_size, void* d_ws, size_t ws_size,
                              hipStream_t stream)
{
    const int*   q     = (const int*)  d_in[0];
    const int*   r     = (const int*)  d_in[1];
    /* d_in[2] = diff (unused) */
    const float* k_emb = (const float*)d_in[3];
    const float* v_emb = (const float*)d_in[4];
    const float* W1    = (const float*)d_in[5];
    const float* b1    = (const float*)d_in[6];
    const float* W2    = (const float*)d_in[7];
    const float* b2    = (const float*)d_in[8];
    const float* Mk    = (const float*)d_in[9];
    const float* Mv0   = (const float*)d_in[10];
    const float* We    = (const float*)d_in[11];
    const float* be    = (const float*)d_in[12];
    const float* Wa    = (const float*)d_in[13];
    const float* ba    = (const float*)d_in[14];
    const float* Wf    = (const float*)d_in[15];
    const float* bf    = (const float*)d_in[16];
    const float* Wp    = (const float*)d_in[17];
    const float* bp    = (const float*)d_in[18];

    float* ws  = (float*)d_ws;
    float* out = (float*)d_out;

    prep_kernel<<<NTOK/TPB, 256, 0, stream>>>(q,r,k_emb,v_emb,W1,b1,W2,b2,Mk,We,be,Wa,ba,ws);
    scan_kernel<<<dim3(NB,NG), 128, 0, stream>>>(Mv0, ws);
    fp_kernel<<<NTOK/TPB, 256, 0, stream>>>(ws, Wf, bf, Wp, bp, out);
}

// Round 5
// 154.779 us; speedup vs baseline: 5.8112x; 2.4712x over previous
//
#include <hip/hip_runtime.h>
#include <hip/hip_bf16.h>
#include <math.h>

#define NUMC 10000
#define DIMS 128
#define SZM  50
#define FD   512
#define NB   64
#define NL   200
#define NTOK (NB*NL)
#define TPB  16     // tokens per block (fp kernel)
#define NG   2      // m-groups in scan
#define MG   25     // m's per group

typedef unsigned short u16;
typedef __attribute__((ext_vector_type(8))) short bf16x8;
typedef __attribute__((ext_vector_type(4))) float f32x4;

// ws layout (float offsets)
#define OFF_K  ((size_t)0)
#define OFF_W  (OFF_K + (size_t)NTOK*DIMS)          // [NTOK][64], m-major 0..49
#define OFF_E  (OFF_W + (size_t)NTOK*64)
#define OFF_A  (OFF_E + (size_t)NTOK*DIMS)
#define OFF_PR (OFF_A + (size_t)NTOK*DIMS)          // [NG][NTOK][DIMS]
#define OFF_PACK (OFF_PR + (size_t)NG*NTOK*DIMS)    // packed bf16 weights (as u16)
// u16 offsets within pack region:
#define PK_W1 0
#define PK_W2 65536      // 16 ks * 8 nb * 64 lanes * 8
#define PK_WE 131072
#define PK_WA 147456     // 4*8*64*8 = 16384 each
#define PK_MK 163840     // 4*4*64*8 = 8192

__device__ __forceinline__ float sigmoidf_(float x){ return 1.0f/(1.0f+expf(-x)); }

// fp32 -> bf16 (RNE, bit-level; values here are well-behaved, no NaN/Inf)
__device__ __forceinline__ u16 f2bf(float f){
    unsigned int b = __float_as_uint(f);
    b += 0x7fffu + ((b >> 16) & 1u);
    return (u16)(b >> 16);
}

// ---------------- pack kernel: W[K][128] fp32 -> B-fragment-order bf16 ----------------
// frag order: P[((ks*NBW + nb)*64 + lane)*8 + j] = W[ks*32 + (lane>>4)*8 + j][nb*16 + (lane&15)]
__device__ __forceinline__ void pack_one(const float* __restrict__ W, u16* __restrict__ P, int u, int nbw){
    int l = u & 63; int t = u >> 6; int nb = t & (nbw-1); int ks = t / nbw;
    int col = nb*16 + (l & 15);
    int kb  = ks*32 + ((l >> 4) << 3);
    u16* dst = P + (size_t)u*8;
    #pragma unroll
    for (int j=0;j<8;j++) dst[j] = f2bf(W[(size_t)(kb+j)*DIMS + col]);
}

__global__ __launch_bounds__(256) void pack_kernel(
    const float* __restrict__ W1, const float* __restrict__ W2,
    const float* __restrict__ We, const float* __restrict__ Wa,
    const float* __restrict__ Mk,
    u16* __restrict__ W1p, u16* __restrict__ W2p,
    u16* __restrict__ Wep, u16* __restrict__ Wap, u16* __restrict__ Mkp)
{
    int gid = blockIdx.x*256 + threadIdx.x;
    if      (gid <  8192) pack_one(W1, W1p, gid,        8);
    else if (gid < 16384) pack_one(W2, W2p, gid- 8192,  8);
    else if (gid < 18432) pack_one(We, Wep, gid-16384,  8);
    else if (gid < 20480) pack_one(Wa, Wap, gid-18432,  8);
    else if (gid < 21504){
        // Mk [50][128] -> B[k=d][col=m], N padded to 64 with zeros
        int u = gid - 20480;
        int l = u & 63; int t = u >> 6; int nb = t & 3; int ks = t >> 2;
        int col = nb*16 + (l & 15);
        int kb  = ks*32 + ((l >> 4) << 3);
        u16* dst = Mkp + (size_t)u*8;
        #pragma unroll
        for (int j=0;j<8;j++) dst[j] = (col < SZM) ? f2bf(Mk[(size_t)col*DIMS + kb + j]) : (u16)0;
    }
}

// ---------------- prep: MFMA GEMMs ----------------
__device__ __forceinline__ bf16x8 ldA(const float* __restrict__ p){
    float4 f0 = *(const float4*)p;
    float4 f1 = *(const float4*)(p+4);
    bf16x8 a;
    a[0]=(short)f2bf(f0.x); a[1]=(short)f2bf(f0.y); a[2]=(short)f2bf(f0.z); a[3]=(short)f2bf(f0.w);
    a[4]=(short)f2bf(f1.x); a[5]=(short)f2bf(f1.y); a[6]=(short)f2bf(f1.z); a[7]=(short)f2bf(f1.w);
    return a;
}
#define MFMA(a,b,c) __builtin_amdgcn_mfma_f32_16x16x32_bf16((a),(b),(c),0,0,0)

__global__ __launch_bounds__(256) void prep_kernel(
    const int* __restrict__ q, const int* __restrict__ r,
    const float* __restrict__ k_emb, const float* __restrict__ v_emb,
    const float* __restrict__ b1, const float* __restrict__ b2,
    const float* __restrict__ be, const float* __restrict__ ba,
    const u16* __restrict__ W1p, const u16* __restrict__ W2p,
    const u16* __restrict__ Wep, const u16* __restrict__ Wap,
    const u16* __restrict__ Mkp,
    float* __restrict__ ws)
{
    __shared__ int qi[32], xi[32];
    __shared__ __align__(16) u16 skb[32][144];   // k bf16 (A for logits)
    __shared__ __align__(16) u16 svb[32][144];   // v bf16 (A for e/a)
    __shared__ float lg[32][68];                 // logits

    const int tid  = threadIdx.x;
    const int base = blockIdx.x * 32;
    if (tid < 32){
        int qq = q[base+tid];
        qi[tid] = qq;
        xi[tid] = qq + NUMC * r[base+tid];
    }
    __syncthreads();

    const int w    = tid >> 6;       // wave 0..3 -> cols [w*32, w*32+32)
    const int l    = tid & 63;
    const int l15  = l & 15;
    const int kgrp = (l >> 4) * 8;
    const int nb0  = 2*w, nb1 = 2*w+1;

    const float* kr0 = k_emb + (size_t)qi[l15]*FD;
    const float* kr1 = k_emb + (size_t)qi[16+l15]*FD;
    const float* vr0 = v_emb + (size_t)xi[l15]*FD;
    const float* vr1 = v_emb + (size_t)xi[16+l15]*FD;

    // ---- phase 1: k = Ek@W1, v = Ev@W2  (M=32, N=128, K=512) ----
    f32x4 kc00={0,0,0,0},kc01={0,0,0,0},kc10={0,0,0,0},kc11={0,0,0,0};
    f32x4 vc00={0,0,0,0},vc01={0,0,0,0},vc10={0,0,0,0},vc11={0,0,0,0};
    #pragma unroll 4
    for (int ks=0; ks<16; ++ks){
        int ko = ks*32 + kgrp;
        bf16x8 ak0 = ldA(kr0+ko), ak1 = ldA(kr1+ko);
        bf16x8 av0 = ldA(vr0+ko), av1 = ldA(vr1+ko);
        bf16x8 b10 = *(const bf16x8*)(W1p + ((size_t)(ks*8+nb0)*64 + l)*8);
        bf16x8 b11 = *(const bf16x8*)(W1p + ((size_t)(ks*8+nb1)*64 + l)*8);
        bf16x8 b20 = *(const bf16x8*)(W2p + ((size_t)(ks*8+nb0)*64 + l)*8);
        bf16x8 b21 = *(const bf16x8*)(W2p + ((size_t)(ks*8+nb1)*64 + l)*8);
        kc00 = MFMA(ak0,b10,kc00); kc01 = MFMA(ak0,b11,kc01);
        kc10 = MFMA(ak1,b10,kc10); kc11 = MFMA(ak1,b11,kc11);
        vc00 = MFMA(av0,b20,vc00); vc01 = MFMA(av0,b21,vc01);
        vc10 = MFMA(av1,b20,vc10); vc11 = MFMA(av1,b21,vc11);
    }
    // epilogue: +bias; k -> ws fp32 + skb bf16 ; v -> svb bf16
    {
        int c0 = w*32 + l15, c1 = w*32 + 16 + l15;
        float bk0 = b1[c0], bk1 = b1[c1], bv0 = b2[c0], bv1 = b2[c1];
        #pragma unroll
        for (int rr=0; rr<4; ++rr){
            int r0 = (l>>4)*4 + rr;        // mr=0 rows
            int r1 = 16 + r0;              // mr=1 rows
            float kv;
            kv = kc00[rr]+bk0; ws[OFF_K+(size_t)(base+r0)*DIMS+c0]=kv; skb[r0][c0]=f2bf(kv);
            kv = kc01[rr]+bk1; ws[OFF_K+(size_t)(base+r0)*DIMS+c1]=kv; skb[r0][c1]=f2bf(kv);
            kv = kc10[rr]+bk0; ws[OFF_K+(size_t)(base+r1)*DIMS+c0]=kv; skb[r1][c0]=f2bf(kv);
            kv = kc11[rr]+bk1; ws[OFF_K+(size_t)(base+r1)*DIMS+c1]=kv; skb[r1][c1]=f2bf(kv);
            svb[r0][c0]=f2bf(vc00[rr]+bv0);
            svb[r0][c1]=f2bf(vc01[rr]+bv1);
            svb[r1][c0]=f2bf(vc10[rr]+bv0);
            svb[r1][c1]=f2bf(vc11[rr]+bv1);
        }
    }
    __syncthreads();

    // ---- phase 2a: logits = k @ Mk^T  (N=64 padded; wave w -> cols w*16..) ----
    {
        f32x4 lc0={0,0,0,0}, lc1={0,0,0,0};
        #pragma unroll
        for (int ks=0; ks<4; ++ks){
            bf16x8 a0 = *(const bf16x8*)&skb[l15   ][ks*32+kgrp];
            bf16x8 a1 = *(const bf16x8*)&skb[16+l15][ks*32+kgrp];
            bf16x8 bm = *(const bf16x8*)(Mkp + ((size_t)(ks*4+w)*64 + l)*8);
            lc0 = MFMA(a0,bm,lc0);
            lc1 = MFMA(a1,bm,lc1);
        }
        int cm = w*16 + l15;
        #pragma unroll
        for (int rr=0; rr<4; ++rr){
            int r0 = (l>>4)*4 + rr;
            lg[r0   ][cm] = lc0[rr];
            lg[16+r0][cm] = lc1[rr];
        }
    }

    // ---- phase 2b: e = sigmoid(v@We+be), a = tanh(v@Wa+ba) (K=128) ----
    {
        f32x4 ec00={0,0,0,0},ec01={0,0,0,0},ec10={0,0,0,0},ec11={0,0,0,0};
        f32x4 ac00={0,0,0,0},ac01={0,0,0,0},ac10={0,0,0,0},ac11={0,0,0,0};
        #pragma unroll
        for (int ks=0; ks<4; ++ks){
            bf16x8 a0 = *(const bf16x8*)&svb[l15   ][ks*32+kgrp];
            bf16x8 a1 = *(const bf16x8*)&svb[16+l15][ks*32+kgrp];
            bf16x8 e0 = *(const bf16x8*)(Wep + ((size_t)(ks*8+nb0)*64 + l)*8);
            bf16x8 e1 = *(const bf16x8*)(Wep + ((size_t)(ks*8+nb1)*64 + l)*8);
            bf16x8 a0w= *(const bf16x8*)(Wap + ((size_t)(ks*8+nb0)*64 + l)*8);
            bf16x8 a1w= *(const bf16x8*)(Wap + ((size_t)(ks*8+nb1)*64 + l)*8);
            ec00 = MFMA(a0,e0,ec00); ec01 = MFMA(a0,e1,ec01);
            ec10 = MFMA(a1,e0,ec10); ec11 = MFMA(a1,e1,ec11);
            ac00 = MFMA(a0,a0w,ac00); ac01 = MFMA(a0,a1w,ac01);
            ac10 = MFMA(a1,a0w,ac10); ac11 = MFMA(a1,a1w,ac11);
        }
        int c0 = w*32 + l15, c1 = w*32 + 16 + l15;
        float beE0 = be[c0], beE1 = be[c1], baA0 = ba[c0], baA1 = ba[c1];
        #pragma unroll
        for (int rr=0; rr<4; ++rr){
            int r0 = (l>>4)*4 + rr;
            int r1 = 16 + r0;
            ws[OFF_E+(size_t)(base+r0)*DIMS+c0] = sigmoidf_(ec00[rr]+beE0);
            ws[OFF_E+(size_t)(base+r0)*DIMS+c1] = sigmoidf_(ec01[rr]+beE1);
            ws[OFF_E+(size_t)(base+r1)*DIMS+c0] = sigmoidf_(ec10[rr]+beE0);
            ws[OFF_E+(size_t)(base+r1)*DIMS+c1] = sigmoidf_(ec11[rr]+beE1);
            ws[OFF_A+(size_t)(base+r0)*DIMS+c0] = tanhf(ac00[rr]+baA0);
            ws[OFF_A+(size_t)(base+r0)*DIMS+c1] = tanhf(ac01[rr]+baA1);
            ws[OFF_A+(size_t)(base+r1)*DIMS+c0] = tanhf(ac10[rr]+baA0);
            ws[OFF_A+(size_t)(base+r1)*DIMS+c1] = tanhf(ac11[rr]+baA1);
        }
    }
    __syncthreads();

    // ---- phase 3: softmax over m (8 lanes/token) ----
    {
        const int t  = tid >> 3;    // 0..31
        const int ml = tid & 7;
        float v[7]; float mx = -1e30f;
        #pragma unroll
        for (int j=0;j<7;j++){
            int m = ml + j*8;
            float x = (m < SZM) ? lg[t][m] : -1e30f;
            v[j] = x; mx = fmaxf(mx, x);
        }
        #pragma unroll
        for (int o=1;o<8;o<<=1) mx = fmaxf(mx, __shfl_xor(mx, o));
        float ex[7]; float sm = 0.f;
        #pragma unroll
        for (int j=0;j<7;j++){
            int m = ml + j*8;
            ex[j] = (m < SZM) ? expf(v[j]-mx) : 0.f;
            sm += ex[j];
        }
        #pragma unroll
        for (int o=1;o<8;o<<=1) sm += __shfl_xor(sm, o);
        float inv = 1.f/sm;
        #pragma unroll
        for (int j=0;j<7;j++){
            int m = ml + j*8;
            if (m < SZM) ws[OFF_W + (size_t)(base+t)*64 + m] = ex[j]*inv;
        }
    }
}

// ---------------- scan (unchanged) ----------------
__global__ __launch_bounds__(128) void scan_kernel(const float* __restrict__ Mv0, float* __restrict__ ws)
{
    const int b = blockIdx.x;
    const int g = blockIdx.y;
    const int d = threadIdx.x;

    const float* wb = ws + OFF_W + (size_t)b*NL*64 + g*MG;
    const float* eb = ws + OFF_E + (size_t)b*NL*DIMS + d;
    const float* ab = ws + OFF_A + (size_t)b*NL*DIMS + d;
    float* pr = ws + OFF_PR + ((size_t)g*NTOK + (size_t)b*NL)*DIMS + d;

    float Mv[MG];
    #pragma unroll
    for (int m=0;m<MG;m++) Mv[m] = Mv0[(g*MG+m)*DIMS + d];

    float wA[MG], wB[MG];
    float eA,aA,eB,aB;
    #pragma unroll
    for (int m=0;m<MG;m++) wA[m]=wb[m];
    eA=eb[0]; aA=ab[0];

    for (int t=0;t<NL;t+=2){
        #pragma unroll
        for (int m=0;m<MG;m++) wB[m]=wb[(size_t)(t+1)*64+m];
        eB=eb[(size_t)(t+1)*DIMS]; aB=ab[(size_t)(t+1)*DIMS];

        float rt=0.f;
        #pragma unroll
        for (int m=0;m<MG;m++){
            float c=wA[m];
            rt=fmaf(c,Mv[m],rt);
            float t1=c*eA, t2=c*aA;
            Mv[m]=Mv[m]+fmaf(-t1,Mv[m],t2);
        }
        pr[(size_t)t*DIMS]=rt;

        if (t+2<NL){
            #pragma unroll
            for (int m=0;m<MG;m++) wA[m]=wb[(size_t)(t+2)*64+m];
            eA=eb[(size_t)(t+2)*DIMS]; aA=ab[(size_t)(t+2)*DIMS];
        }

        rt=0.f;
        #pragma unroll
        for (int m=0;m<MG;m++){
            float c=wB[m];
            rt=fmaf(c,Mv[m],rt);
            float t1=c*eB, t2=c*aB;
            Mv[m]=Mv[m]+fmaf(-t1,Mv[m],t2);
        }
        pr[(size_t)(t+1)*DIMS]=rt;
    }
}

// ---------------- fp (unchanged) ----------------
__global__ __launch_bounds__(256) void fp_kernel(
    const float* __restrict__ ws,
    const float* __restrict__ Wf, const float* __restrict__ bf,
    const float* __restrict__ Wp, const float* __restrict__ bp,
    float* __restrict__ out)
{
    __shared__ float sr [TPB][DIMS+4];
    __shared__ float skk[TPB][DIMS+4];
    __shared__ float pf [TPB][DIMS+4];
    const int tid  = threadIdx.x;
    const int d    = tid & 127;
    const int half = tid >> 7;
    const int base = blockIdx.x*TPB;
    const int t0   = half*8;

    #pragma unroll
    for (int t=0;t<8;t++){
        size_t tok=(size_t)base+t0+t;
        sr [t0+t][d]= ws[OFF_PR + tok*DIMS + d] + ws[OFF_PR + ((size_t)NTOK+tok)*DIMS + d];
        skk[t0+t][d]= ws[OFF_K + tok*DIMS + d];
    }
    __syncthreads();

    float facc[8];
    {
        float bfj=bf[d];
        #pragma unroll
        for (int t=0;t<8;t++) facc[t]=bfj;
    }
    for (int i=0;i<DIMS;i+=4){
        float wt0=Wf[(i+0)*DIMS+d],wt1=Wf[(i+1)*DIMS+d],wt2=Wf[(i+2)*DIMS+d],wt3=Wf[(i+3)*DIMS+d];
        float wb0=Wf[(DIMS+i+0)*DIMS+d],wb1=Wf[(DIMS+i+1)*DIMS+d],wb2=Wf[(DIMS+i+2)*DIMS+d],wb3=Wf[(DIMS+i+3)*DIMS+d];
        #pragma unroll
        for (int t=0;t<8;t++){
            float4 r4=*(const float4*)&sr [t0+t][i];
            float4 k4=*(const float4*)&skk[t0+t][i];
            facc[t]=fmaf(r4.x,wt0,fmaf(r4.y,wt1,fmaf(r4.z,wt2,fmaf(r4.w,wt3,facc[t]))));
            facc[t]=fmaf(k4.x,wb0,fmaf(k4.y,wb1,fmaf(k4.z,wb2,fmaf(k4.w,wb3,facc[t]))));
        }
    }
    {
        float wpj=Wp[d];
        #pragma unroll
        for (int t=0;t<8;t++) pf[t0+t][d]=tanhf(facc[t])*wpj;
    }
    __syncthreads();
    if (tid<TPB){
        float s=bp[0];
        for (int jj=0;jj<DIMS;jj++) s+=pf[tid][jj];
        out[base+tid]=sigmoidf_(s);
    }
}

extern "C" void kernel_launch(void* const* d_in, const int* in_sizes, int n_in,
                              void* d_out, int out_size, void* d_ws, size_t ws_size,
                              hipStream_t stream)
{
    const int*   q     = (const int*)  d_in[0];
    const int*   r     = (const int*)  d_in[1];
    /* d_in[2] = diff (unused) */
    const float* k_emb = (const float*)d_in[3];
    const float* v_emb = (const float*)d_in[4];
    const float* W1    = (const float*)d_in[5];
    const float* b1    = (const float*)d_in[6];
    const float* W2    = (const float*)d_in[7];
    const float* b2    = (const float*)d_in[8];
    const float* Mk    = (const float*)d_in[9];
    const float* Mv0   = (const float*)d_in[10];
    const float* We    = (const float*)d_in[11];
    const float* be    = (const float*)d_in[12];
    const float* Wa    = (const float*)d_in[13];
    const float* ba    = (const float*)d_in[14];
    const float* Wf    = (const float*)d_in[15];
    const float* bf    = (const float*)d_in[16];
    const float* Wp    = (const float*)d_in[17];
    const float* bp    = (const float*)d_in[18];

    float* ws  = (float*)d_ws;
    float* out = (float*)d_out;
    u16* pk  = (u16*)(ws + OFF_PACK);
    u16* W1p = pk + PK_W1;
    u16* W2p = pk + PK_W2;
    u16* Wep = pk + PK_WE;
    u16* Wap = pk + PK_WA;
    u16* Mkp = pk + PK_MK;

    pack_kernel<<<84, 256, 0, stream>>>(W1,W2,We,Wa,Mk, W1p,W2p,Wep,Wap,Mkp);
    prep_kernel<<<NTOK/32, 256, 0, stream>>>(q,r,k_emb,v_emb,b1,b2,be,ba,W1p,W2p,Wep,Wap,Mkp,ws);
    scan_kernel<<<dim3(NB,NG), 128, 0, stream>>>(Mv0, ws);
    fp_kernel<<<NTOK/TPB, 256, 0, stream>>>(ws, Wf, bf, Wp, bp, out);
}